// Round 12
// baseline (364.674 us; speedup 1.0000x reference)
//
#include <hip/hip_runtime.h>
#include <hip/hip_fp16.h>
#include <hip/hip_cooperative_groups.h>

// GCN 2-layer: N=100000, F=128 -> H=16 (relu) -> C=40, E=3200000.
//
// R13 = R12 (best, 228.5us) with the 5-kernel partition build fused into ONE
// cooperative kernel (k_build) using grid.sync():
//   phase 1: load chunk ONCE into registers, LDS bucket-histogram -> hist
//   phase 3: global exclusive scan of hist in-place (blocks 0..NSEG-1)
//   phase 5: scan of partials (block 0)
//   phase 7: rank-scatter from the SAME registers via LDS staging -> eb
//   phase 9: per-bucket degree -> rp, dinv (strided over buckets)
// Saves: hist's separate 12.8MB dst read, part's 25.6MB dst+src re-read,
// 4 kernel launches + gaps. R12 evidence: build machinery ~50us across 5
// kernels, none at a HW floor; csrg1/csrg2 (88us) sit at the 2E random-txn
// floor and are kept verbatim (part scan shift 9 -> 10).
// R10 lesson kept: per-node sums are register accumulation over node-sorted
// edges, never scattered LDS atomic adds.
//
// Math: norm(s->d) = dinv[s]*dinv[d], self-loop norm = dinv[n]^2.
//   h1p = (x@W1)*dinv            (pre-scaled => no dinv[src] gather per edge)
//   agg1[n] = dinv[n]*(h1p[n] + sum_{s in in(n)} h1p[s])
//   r1p[n]  = relu(agg1[n]+b1)*dinv[n]          (fused in csrg1 epilogue)
//   agg2[n] = dinv[n]*(r1p[n] + sum r1p[s])
//   out[n]  = agg2[n]@W2 + b2                   (fused in csrg2 epilogue)

#define N_NODES 100000
#define F_IN    128
#define H_MID   16
#define C_OUT   40
#define N_EDGES 3200000

#define EC      12800                // edges per chunk; 250 blocks exactly
#define EBLK    250                  // N_EDGES / EC
#define KPT     13                   // ceil(EC / 1024)
#define NBUK    782                  // buckets of 128 nodes: covers 0..100095
#define M_HIST  (NBUK * EBLK)        // 195500
#define NSEG    191                  // ceil(M_HIST / 1024)
#define SRC_MASK 0x1FFFF             // src < 100000 < 2^17
#define NSTRIDE 100352               // padded node stride
#define CAP_H   5632                 // per-bucket esl (mean 4096, sd ~64)

namespace cg = cooperative_groups;

// ---------------- fused partition build (cooperative, 1 launch) ------------

__global__ void __launch_bounds__(1024) k_build(
    const int* __restrict__ src, const int* __restrict__ dst,
    int* __restrict__ hist, int* __restrict__ part, int* __restrict__ eb,
    int* __restrict__ rp, float* __restrict__ dinv) {
    __shared__ int cnt[NBUK];
    __shared__ int dlt[NBUK];
    __shared__ int cr[NBUK];
    __shared__ int lscn[1024];
    __shared__ int sval[EC];
    __shared__ int spos[EC];
    cg::grid_group grid = cg::this_grid();
    int t = threadIdx.x, blk = blockIdx.x;
    int e0 = blk * EC;

    // ---- phase 1: load chunk to registers + LDS histogram -> hist
    for (int b = t; b < NBUK; b += 1024) cnt[b] = 0;
    __syncthreads();
    int d[KPT], s[KPT];
#pragma unroll
    for (int k = 0; k < KPT; ++k) {
        int off = k * 1024 + t;
        if (off < EC) {
            d[k] = __builtin_nontemporal_load(dst + e0 + off);
            s[k] = __builtin_nontemporal_load(src + e0 + off);
        } else { d[k] = 0; s[k] = 0; }
    }
#pragma unroll
    for (int k = 0; k < KPT; ++k)
        if (k * 1024 + t < EC) atomicAdd(&cnt[d[k] >> 7], 1);
    __syncthreads();
    for (int b = t; b < NBUK; b += 1024) hist[b * EBLK + blk] = cnt[b];
    grid.sync();

    // ---- phase 3: exclusive scan of hist (segments of 1024)
    if (blk < NSEG) {
        int i = blk * 1024 + t;
        int v = (i < M_HIST) ? hist[i] : 0;
        lscn[t] = v;
        __syncthreads();
        for (int off = 1; off < 1024; off <<= 1) {
            int x = (t >= off) ? lscn[t - off] : 0;
            __syncthreads();
            lscn[t] += x;
            __syncthreads();
        }
        if (i < M_HIST) hist[i] = lscn[t] - v;
        if (t == 1023) part[blk] = lscn[1023];
    }
    grid.sync();

    // ---- phase 5: scan of the NSEG partials (block 0)
    if (blk == 0) {
        int v = (t < NSEG) ? part[t] : 0;
        lscn[t] = v;
        __syncthreads();
        for (int off = 1; off < 1024; off <<= 1) {
            int x = (t >= off) ? lscn[t - off] : 0;
            __syncthreads();
            lscn[t] += x;
            __syncthreads();
        }
        if (t < NSEG) part[t] = lscn[t] - v;
    }
    grid.sync();

    // ---- phase 7: rank-scatter from registers via LDS staging -> eb
    lscn[t] = (t < NBUK) ? cnt[t] : 0;
    __syncthreads();
    for (int off = 1; off < 1024; off <<= 1) {
        int x = (t >= off) ? lscn[t - off] : 0;
        __syncthreads();
        lscn[t] += x;
        __syncthreads();
    }
    for (int b = t; b < NBUK; b += 1024) {
        int idx = b * EBLK + blk;
        int gb = hist[idx] + part[idx >> 10];  // global base of (b, blk) run
        int lb = lscn[b] - cnt[b];             // local base (exclusive)
        dlt[b] = gb - lb;
        cr[b] = lb;
    }
    __syncthreads();
#pragma unroll
    for (int k = 0; k < KPT; ++k) {
        if (k * 1024 + t < EC) {
            int bk = d[k] >> 7;
            int lr = atomicAdd(&cr[bk], 1);              // LDS return-atomic
            sval[lr] = ((d[k] & 127) << 17) | s[k];
            spos[lr] = lr + dlt[bk];
        }
    }
    __syncthreads();
    for (int i = t; i < EC; i += 1024)
        eb[spos[i]] = sval[i];                 // coalesced within ~16-edge runs
    grid.sync();

    // ---- phase 9: per-bucket degree -> rp, dinv (reuse cnt/lscn as deg/scan)
    for (int b = blk; b < NBUK; b += gridDim.x) {
        int i0 = b * EBLK;
        int bb = hist[i0] + part[i0 >> 10];
        int bn = (b + 1 < NBUK) ? (hist[i0 + EBLK] + part[(i0 + EBLK) >> 10]) : N_EDGES;
        int ecnt = bn - bb;
        if (t < 128) cnt[t] = 0;
        __syncthreads();
        for (int i = t; i < ecnt; i += 1024)
            atomicAdd(&cnt[eb[bb + i] >> 17], 1);
        __syncthreads();
        if (t < 128) lscn[t] = cnt[t];
        __syncthreads();
        for (int off = 1; off < 128; off <<= 1) {
            int x = (t < 128 && t >= off) ? lscn[t - off] : 0;
            __syncthreads();
            if (t < 128) lscn[t] += x;
            __syncthreads();
        }
        if (t < 128) {
            int ex = lscn[t] - cnt[t];         // exclusive within bucket
            int node = b * 128 + t;            // < 100096
            rp[node] = bb + ex;                // rp[100000] == N_EDGES naturally
            dinv[node] = rsqrtf(1.0f + (float)cnt[t]);
        }
        __syncthreads();
    }
}

// ---------------- dense kernels (R12, proven) ------------------------

typedef float f4 __attribute__((ext_vector_type(4)));

// 16 nodes per block, 256 threads = 16 nodes x 16 out-features.
// h1p = fp16( (x@W1) * dinv[node] )
__global__ void __launch_bounds__(256) k_gemm1(
    const float* __restrict__ x, const float* __restrict__ W1,
    const float* __restrict__ dinv, __half* __restrict__ h1p) {
    __shared__ float w[F_IN * H_MID];   // 8 KB
    __shared__ float xs[16 * 132];      // padded rows: no 128-stride conflicts
    int t = threadIdx.x;
    for (int i = t; i < F_IN * H_MID; i += 256) w[i] = W1[i];
    int tile = blockIdx.x;              // 6250 tiles, exact
    const f4* xg = (const f4*)(x + (size_t)tile * 16 * F_IN);
    f4* xs4 = (f4*)xs;                  // row stride 33 float4
    for (int i = t; i < 512; i += 256) {
        int r = i >> 5, c4 = i & 31;
        xs4[r * 33 + c4] = __builtin_nontemporal_load(xg + r * 32 + c4);
    }
    __syncthreads();
    int node = t >> 4, j = t & 15;
    const float* xr = xs + node * 132;
    float acc = 0.f;
#pragma unroll 8
    for (int k = 0; k < F_IN; ++k) acc += xr[k] * w[k * H_MID + j];
    int g = tile * 16 + node;
    h1p[(size_t)g * H_MID + j] = __float2half(acc * dinv[g]);
}

// FUSED layer 1: per-bucket LDS rank-sort + register gather + relu/bias.
// r1p[n] = fp16( relu(dinv[n]*(h1p[n] + sum h1p[s]) + b1) * dinv[n] )
__global__ void __launch_bounds__(1024) k_csrg1(
    const int* __restrict__ hist, const int* __restrict__ part,
    const int* __restrict__ eb, const int* __restrict__ rp,
    const float* __restrict__ dinv, const __half* __restrict__ h1p,
    const float* __restrict__ b1, __half* __restrict__ r1p) {
    __shared__ int base[129];
    __shared__ int cw[128];
    __shared__ int esl[CAP_H];
    int b = blockIdx.x, t = threadIdx.x;
    int i0 = b * EBLK;
    int bb = hist[i0] + part[i0 >> 10];
    int bn = (b + 1 < NBUK) ? (hist[i0 + EBLK] + part[(i0 + EBLK) >> 10]) : N_EDGES;
    int ecnt = bn - bb;
    int n0 = b * 128;
    if (t < 128) {
        int lb = rp[n0 + t] - bb;      // bucket-local segment start
        base[t] = lb;
        cw[t] = lb;
    }
    if (t == 128) base[128] = ecnt;
    __syncthreads();
    int g = t >> 4, j = t & 15;        // 64 groups x 16 feature-lanes
    if (ecnt <= CAP_H) {
        for (int i = t; i < ecnt; i += 1024) {          // rank-sort into esl
            int v = __builtin_nontemporal_load(eb + bb + i);
            int r = atomicAdd(&cw[v >> 17], 1);          // LDS return-atomic
            esl[r] = v & SRC_MASK;
        }
        __syncthreads();
        for (int nd = g; nd < 128; nd += 64) {           // register gather
            int node = n0 + nd;
            if (node >= N_NODES) continue;
            float dv = dinv[node];
            int beg = base[nd], end = base[nd + 1];
            float acc = __half2float(h1p[(size_t)node * H_MID + j]);  // self loop
            int e = beg;
            for (; e + 8 <= end; e += 8) {
                int s0 = esl[e],     s1 = esl[e + 1], s2 = esl[e + 2], s3 = esl[e + 3];
                int s4 = esl[e + 4], s5 = esl[e + 5], s6 = esl[e + 6], s7 = esl[e + 7];
                acc += __half2float(h1p[(size_t)s0 * H_MID + j])
                     + __half2float(h1p[(size_t)s1 * H_MID + j])
                     + __half2float(h1p[(size_t)s2 * H_MID + j])
                     + __half2float(h1p[(size_t)s3 * H_MID + j])
                     + __half2float(h1p[(size_t)s4 * H_MID + j])
                     + __half2float(h1p[(size_t)s5 * H_MID + j])
                     + __half2float(h1p[(size_t)s6 * H_MID + j])
                     + __half2float(h1p[(size_t)s7 * H_MID + j]);
            }
            for (; e < end; ++e) acc += __half2float(h1p[(size_t)esl[e] * H_MID + j]);
            float a = dv * acc;
            unsigned short o = __half_as_ushort(__float2half(fmaxf(a + b1[j], 0.f) * dv));
            __builtin_nontemporal_store(o, (unsigned short*)(r1p + (size_t)node * H_MID + j));
        }
    } else {
        // statistically-unreachable fallback (ecnt > +24 sigma): O(n*e) scan
        for (int nd = g; nd < 128; nd += 64) {
            int node = n0 + nd;
            if (node >= N_NODES) continue;
            float dv = dinv[node];
            float acc = __half2float(h1p[(size_t)node * H_MID + j]);
            for (int i = 0; i < ecnt; ++i) {
                int v = eb[bb + i];
                if ((v >> 17) == nd)
                    acc += __half2float(h1p[(size_t)(v & SRC_MASK) * H_MID + j]);
            }
            float a = dv * acc;
            unsigned short o = __half_as_ushort(__float2half(fmaxf(a + b1[j], 0.f) * dv));
            __builtin_nontemporal_store(o, (unsigned short*)(r1p + (size_t)node * H_MID + j));
        }
    }
}

// FUSED layer 2: per-bucket LDS rank-sort + register gather + @W2 + b2.
__global__ void __launch_bounds__(1024) k_csrg2(
    const int* __restrict__ hist, const int* __restrict__ part,
    const int* __restrict__ eb, const int* __restrict__ rp,
    const float* __restrict__ dinv, const __half* __restrict__ r1p,
    const float* __restrict__ W2, const float* __restrict__ b2,
    float* __restrict__ out) {
    __shared__ int base[129];
    __shared__ int cw[128];
    __shared__ int esl[CAP_H];
    __shared__ float a2[128 * 17];     // padded
    __shared__ float w2[H_MID * C_OUT];
    __shared__ float b2l[C_OUT];
    int b = blockIdx.x, t = threadIdx.x;
    int i0 = b * EBLK;
    int bb = hist[i0] + part[i0 >> 10];
    int bn = (b + 1 < NBUK) ? (hist[i0 + EBLK] + part[(i0 + EBLK) >> 10]) : N_EDGES;
    int ecnt = bn - bb;
    int n0 = b * 128;
    if (t < H_MID * C_OUT) w2[t] = W2[t];
    if (t >= 1024 - C_OUT) b2l[t - (1024 - C_OUT)] = b2[t - (1024 - C_OUT)];
    if (t < 128) {
        int lb = rp[n0 + t] - bb;
        base[t] = lb;
        cw[t] = lb;
    }
    if (t == 128) base[128] = ecnt;
    __syncthreads();
    int g = t >> 4, j = t & 15;
    if (ecnt <= CAP_H) {
        for (int i = t; i < ecnt; i += 1024) {
            int v = __builtin_nontemporal_load(eb + bb + i);
            int r = atomicAdd(&cw[v >> 17], 1);
            esl[r] = v & SRC_MASK;
        }
        __syncthreads();
        for (int nd = g; nd < 128; nd += 64) {
            int node = n0 + nd;
            float dv = (node < N_NODES) ? dinv[node] : 0.f;
            int beg = base[nd], end = base[nd + 1];
            float acc = (node < N_NODES) ? __half2float(r1p[(size_t)node * H_MID + j]) : 0.f;
            int e = beg;
            for (; e + 8 <= end; e += 8) {
                int s0 = esl[e],     s1 = esl[e + 1], s2 = esl[e + 2], s3 = esl[e + 3];
                int s4 = esl[e + 4], s5 = esl[e + 5], s6 = esl[e + 6], s7 = esl[e + 7];
                acc += __half2float(r1p[(size_t)s0 * H_MID + j])
                     + __half2float(r1p[(size_t)s1 * H_MID + j])
                     + __half2float(r1p[(size_t)s2 * H_MID + j])
                     + __half2float(r1p[(size_t)s3 * H_MID + j])
                     + __half2float(r1p[(size_t)s4 * H_MID + j])
                     + __half2float(r1p[(size_t)s5 * H_MID + j])
                     + __half2float(r1p[(size_t)s6 * H_MID + j])
                     + __half2float(r1p[(size_t)s7 * H_MID + j]);
            }
            for (; e < end; ++e) acc += __half2float(r1p[(size_t)esl[e] * H_MID + j]);
            a2[nd * 17 + j] = dv * acc;                  // agg2
        }
    } else {
        for (int nd = g; nd < 128; nd += 64) {
            int node = n0 + nd;
            float dv = (node < N_NODES) ? dinv[node] : 0.f;
            float acc = (node < N_NODES) ? __half2float(r1p[(size_t)node * H_MID + j]) : 0.f;
            for (int i = 0; i < ecnt; ++i) {
                int v = eb[bb + i];
                if ((v >> 17) == nd)
                    acc += __half2float(r1p[(size_t)(v & SRC_MASK) * H_MID + j]);
            }
            a2[nd * 17 + j] = dv * acc;
        }
    }
    __syncthreads();
    for (int idx = t; idx < 128 * C_OUT; idx += 1024) {
        int nd = idx / C_OUT, c = idx - nd * C_OUT;
        int node = n0 + nd;
        if (node < N_NODES) {
            float s = b2l[c];
#pragma unroll
            for (int jj = 0; jj < H_MID; ++jj) s += a2[nd * 17 + jj] * w2[jj * C_OUT + c];
            __builtin_nontemporal_store(s, &out[(size_t)node * C_OUT + c]);
        }
    }
}

extern "C" void kernel_launch(void* const* d_in, const int* in_sizes, int n_in,
                              void* d_out, int out_size, void* d_ws, size_t ws_size,
                              hipStream_t stream) {
    const float* x  = (const float*)d_in[0];
    const int*   ei = (const int*)d_in[1];     // [2, E]: row 0 = src, row 1 = dst
    const float* W1 = (const float*)d_in[2];
    const float* b1 = (const float*)d_in[3];
    const float* W2 = (const float*)d_in[4];
    const float* b2 = (const float*)d_in[5];
    float* out = (float*)d_out;

    const int* src = ei;
    const int* dst = ei + N_EDGES;

    // ws layout (4B units), ~16.8 MiB -- all in d_ws (csrg2 reads eb while
    // writing out, so d_out is not used as scratch):
    //   rp[100352] | dinv[100352] | h1p[NSTRIDE*16 half] | r1p[same] |
    //   eb[3.2M] | hist[195584] | part[1024]
    int* rp     = (int*)d_ws;
    float* dinv = (float*)(rp + NSTRIDE);
    __half* h1p = (__half*)(dinv + NSTRIDE);
    __half* r1p = h1p + (size_t)NSTRIDE * H_MID;
    int* eb     = (int*)(r1p + (size_t)NSTRIDE * H_MID);
    int* hist   = eb + N_EDGES;
    int* part   = hist + 195584;

    {
        const int* src_a = src;
        const int* dst_a = dst;
        int* hist_a = hist;
        int* part_a = part;
        int* eb_a = eb;
        int* rp_a = rp;
        float* dinv_a = dinv;
        void* args[] = {(void*)&src_a, (void*)&dst_a, (void*)&hist_a,
                        (void*)&part_a, (void*)&eb_a, (void*)&rp_a,
                        (void*)&dinv_a};
        hipLaunchCooperativeKernel((const void*)k_build, dim3(EBLK), dim3(1024),
                                   args, 0, stream);
    }
    k_gemm1<<<N_NODES / 16, 256, 0, stream>>>(x, W1, dinv, h1p);
    k_csrg1<<<NBUK, 1024, 0, stream>>>(hist, part, eb, rp, dinv, h1p, b1, r1p);
    k_csrg2<<<NBUK, 1024, 0, stream>>>(hist, part, eb, rp, dinv, r1p, W2, b2, out);
}

// Round 14
// 225.988 us; speedup vs baseline: 1.6137x; 1.6137x over previous
//
#include <hip/hip_runtime.h>
#include <hip/hip_fp16.h>

// GCN 2-layer: N=100000, F=128 -> H=16 (relu) -> C=40, E=3200000.
//
// R15 = R14 resubmitted (R13's bench died with "container failed twice" --
// infra error, no kernel signal; audit found no OOB/launch hazard).
// R14 = R12 (best-known-good, 228.5us) + {gemm1 overlapped with k_hist}:
// gemm1 computes UNSCALED h1u = x@W1 (fp32, d_out scratch) fused into
// k_hist's launch as extra blocks (391 hist-blocks + 6250 gemm-tiles, role
// split on blockIdx): hist is mem/LDS-atomic-bound, gemm is VALU/LDS-bound
// -- complementary pipes, gemm blocks backfill as hist drains. k_degrp then
// scales h1p = fp16(h1u * dinv) as a contiguous epilogue (identical numerics
// to R12: fp32 product, single fp16 rounding).
// R10 lesson kept: per-node sums are register accumulation over node-sorted
// edges, never scattered LDS atomic adds.
// R13 lesson kept: no cooperative mega-fusion (grid.sync pinned 1 block/CU).
//
// Math: norm(s->d) = dinv[s]*dinv[d], self-loop norm = dinv[n]^2.
//   h1p = (x@W1)*dinv            (pre-scaled => no dinv[src] gather per edge)
//   agg1[n] = dinv[n]*(h1p[n] + sum_{s in in(n)} h1p[s])
//   r1p[n]  = relu(agg1[n]+b1)*dinv[n]          (fused in csrg1 epilogue)
//   agg2[n] = dinv[n]*(r1p[n] + sum r1p[s])
//   out[n]  = agg2[n]@W2 + b2                   (fused in csrg2 epilogue)

#define N_NODES 100000
#define F_IN    128
#define H_MID   16
#define C_OUT   40
#define N_EDGES 3200000

#define EC      8192                 // edges per chunk (hist / k_part block)
#define EBLK    391                  // ceil(N_EDGES / EC)
#define NBUK    782                  // buckets of 128 nodes: covers 0..100095
#define M_HIST  (NBUK * EBLK)        // 305762
#define NPART   598                  // ceil(M_HIST / 512)
#define SRC_MASK 0x1FFFF             // src < 100000 < 2^17
#define NSTRIDE 100352               // padded node stride
#define CAP_H   5632                 // per-bucket esl (mean 4096, sd ~64)
#define GEMM_TILES 6250              // N_NODES / 16

typedef float f4 __attribute__((ext_vector_type(4)));

// ---------------- fused: edge histogram (391 blocks) + x@W1 (6250 tiles) ---

__global__ void __launch_bounds__(256) k_histgemm(
    const int* __restrict__ dst, int* __restrict__ hist,
    const float* __restrict__ x, const float* __restrict__ W1,
    float* __restrict__ h1u) {
    __shared__ __align__(16) char smem[16640];
    int t = threadIdx.x, blk = blockIdx.x;
    if (blk < EBLK) {
        // ---- histogram role
        int* h = (int*)smem;
        for (int i = t; i < NBUK; i += 256) h[i] = 0;
        __syncthreads();
        int e0 = blk * EC;
#pragma unroll
        for (int i = 0; i < EC / 256; ++i) {
            int e = e0 + i * 256 + t;
            if (e < N_EDGES)
                atomicAdd(&h[__builtin_nontemporal_load(dst + e) >> 7], 1);
        }
        __syncthreads();
        for (int b = t; b < NBUK; b += 256) hist[b * EBLK + blk] = h[b];
    } else {
        // ---- gemm role: 16 nodes x 16 feats, UNSCALED fp32 output
        float* w  = (float*)smem;            // 8192 B
        float* xs = (float*)(smem + 8192);   // 16*132*4 = 8448 B
        int tile = blk - EBLK;
        for (int i = t; i < F_IN * H_MID; i += 256) w[i] = W1[i];
        const f4* xg = (const f4*)(x + (size_t)tile * 16 * F_IN);
        f4* xs4 = (f4*)xs;                   // row stride 33 float4
        for (int i = t; i < 512; i += 256) {
            int r = i >> 5, c4 = i & 31;
            xs4[r * 33 + c4] = __builtin_nontemporal_load(xg + r * 32 + c4);
        }
        __syncthreads();
        int node = t >> 4, j = t & 15;
        const float* xr = xs + node * 132;
        float acc = 0.f;
#pragma unroll 8
        for (int k = 0; k < F_IN; ++k) acc += xr[k] * w[k * H_MID + j];
        int g = tile * 16 + node;
        h1u[(size_t)g * H_MID + j] = acc;
    }
}

// block-local exclusive scan over the linear hist array (bucket-major)
__global__ void __launch_bounds__(512) k_scanA(int* __restrict__ hist,
                                               int* __restrict__ part) {
    __shared__ int s[512];
    int t = threadIdx.x;
    int i = blockIdx.x * 512 + t;
    int v = (i < M_HIST) ? hist[i] : 0;
    s[t] = v;
    __syncthreads();
    for (int off = 1; off < 512; off <<= 1) {
        int x = (t >= off) ? s[t - off] : 0;
        __syncthreads();
        s[t] += x;
        __syncthreads();
    }
    if (i < M_HIST) hist[i] = s[t] - v;
    if (t == 511) part[blockIdx.x] = s[511];
}

// exclusive scan of the NPART block sums; hist stays block-local-exclusive,
// consumers add part[idx>>9] on the fly.
__global__ void __launch_bounds__(1024) k_scanB(int* __restrict__ part) {
    __shared__ int s[1024];
    int t = threadIdx.x;
    int v = (t < NPART) ? part[t] : 0;
    s[t] = v;
    __syncthreads();
    for (int off = 1; off < 1024; off <<= 1) {
        int x = (t >= off) ? s[t - off] : 0;
        __syncthreads();
        s[t] += x;
        __syncthreads();
    }
    if (t < NPART) part[t] = s[t] - v;
}

// partition edges into 128-node buckets via block-local LDS counting sort,
// then coalesced drain: eb[pos] = (loc7<<17)|src17.   (R12, proven)
__global__ void __launch_bounds__(1024) k_part(
    const int* __restrict__ src, const int* __restrict__ dst,
    const int* __restrict__ hist, const int* __restrict__ part,
    int* __restrict__ eb) {
    __shared__ int cnt[NBUK];
    __shared__ int scn[1024];
    __shared__ int dlt[NBUK];
    __shared__ int cr[NBUK];
    __shared__ int sval[EC];
    __shared__ int spos[EC];
    int t = threadIdx.x, blk = blockIdx.x;
    for (int b = t; b < NBUK; b += 1024) cnt[b] = 0;
    __syncthreads();
    int e0 = blk * EC;
    int d[8], s[8], bk[8];
    bool val[8];
#pragma unroll
    for (int k = 0; k < 8; ++k) {
        int e = e0 + k * 1024 + t;
        val[k] = (e < N_EDGES);
        d[k] = val[k] ? __builtin_nontemporal_load(dst + e) : 0;
        s[k] = val[k] ? __builtin_nontemporal_load(src + e) : 0;
        bk[k] = d[k] >> 7;
    }
#pragma unroll
    for (int k = 0; k < 8; ++k)
        if (val[k]) atomicAdd(&cnt[bk[k]], 1);
    __syncthreads();
    scn[t] = (t < NBUK) ? cnt[t] : 0;
    __syncthreads();
    for (int off = 1; off < 1024; off <<= 1) {
        int x = (t >= off) ? scn[t - off] : 0;
        __syncthreads();
        scn[t] += x;
        __syncthreads();
    }
    for (int b = t; b < NBUK; b += 1024) {
        int idx = b * EBLK + blk;
        int gb = hist[idx] + part[idx >> 9];   // global base of (b, blk) run
        int lb = scn[b] - cnt[b];              // local base (exclusive)
        dlt[b] = gb - lb;
        cr[b] = lb;
    }
    __syncthreads();
#pragma unroll
    for (int k = 0; k < 8; ++k) {
        if (val[k]) {
            int lr = atomicAdd(&cr[bk[k]], 1);           // LDS return-atomic
            sval[lr] = ((d[k] & 127) << 17) | s[k];
            spos[lr] = lr + dlt[bk[k]];
        }
    }
    __syncthreads();
    int n = (e0 + EC <= N_EDGES) ? EC : (N_EDGES - e0);
    for (int i = t; i < n; i += 1024)
        eb[spos[i]] = sval[i];                 // coalesced within ~10-edge runs
}

// per-bucket degree -> rp + dinv, THEN scale epilogue: h1p = fp16(h1u*dinv).
__global__ void __launch_bounds__(512) k_degrp(
    const int* __restrict__ hist, const int* __restrict__ part,
    const int* __restrict__ eb, const float* __restrict__ h1u,
    int* __restrict__ rp, float* __restrict__ dinv, __half* __restrict__ h1p) {
    __shared__ int deg[128], scn[128];
    __shared__ float sdv[128];
    int b = blockIdx.x, t = threadIdx.x;
    int i0 = b * EBLK;
    int bb = hist[i0] + part[i0 >> 9];
    int bn = (b + 1 < NBUK) ? (hist[i0 + EBLK] + part[(i0 + EBLK) >> 9]) : N_EDGES;
    int ecnt = bn - bb;
    if (t < 128) deg[t] = 0;
    __syncthreads();
    for (int i = t; i < ecnt; i += 512)
        atomicAdd(&deg[__builtin_nontemporal_load(eb + bb + i) >> 17], 1);
    __syncthreads();
    if (t < 128) scn[t] = deg[t];
    __syncthreads();
    for (int off = 1; off < 128; off <<= 1) {
        int x = (t < 128 && t >= off) ? scn[t - off] : 0;
        __syncthreads();
        if (t < 128) scn[t] += x;
        __syncthreads();
    }
    if (t < 128) {
        int ex = scn[t] - deg[t];              // exclusive within bucket
        int node = b * 128 + t;                // < 100096
        float dv = rsqrtf(1.0f + (float)deg[t]);
        rp[node] = bb + ex;
        dinv[node] = dv;
        sdv[t] = dv;
    }
    __syncthreads();
    // scale epilogue: contiguous 128x16 rows (identical numerics to R12:
    // fp32 acc * fp32 dinv -> single fp16 rounding)
    int n0 = b * 128;
    for (int i = t; i < 128 * H_MID; i += 512) {
        int node = n0 + (i >> 4);
        if (node < N_NODES) {
            float v = h1u[(size_t)n0 * H_MID + i] * sdv[i >> 4];
            unsigned short o = __half_as_ushort(__float2half(v));
            __builtin_nontemporal_store(o, (unsigned short*)(h1p + (size_t)n0 * H_MID + i));
        }
    }
}

// FUSED layer 1: per-bucket LDS rank-sort + register gather + relu/bias.
// r1p[n] = fp16( relu(dinv[n]*(h1p[n] + sum h1p[s]) + b1) * dinv[n] )
__global__ void __launch_bounds__(1024) k_csrg1(
    const int* __restrict__ hist, const int* __restrict__ part,
    const int* __restrict__ eb, const int* __restrict__ rp,
    const float* __restrict__ dinv, const __half* __restrict__ h1p,
    const float* __restrict__ b1, __half* __restrict__ r1p) {
    __shared__ int base[129];
    __shared__ int cw[128];
    __shared__ int esl[CAP_H];
    int b = blockIdx.x, t = threadIdx.x;
    int i0 = b * EBLK;
    int bb = hist[i0] + part[i0 >> 9];
    int bn = (b + 1 < NBUK) ? (hist[i0 + EBLK] + part[(i0 + EBLK) >> 9]) : N_EDGES;
    int ecnt = bn - bb;
    int n0 = b * 128;
    if (t < 128) {
        int lb = rp[n0 + t] - bb;      // bucket-local segment start
        base[t] = lb;
        cw[t] = lb;
    }
    if (t == 128) base[128] = ecnt;
    __syncthreads();
    int g = t >> 4, j = t & 15;        // 64 groups x 16 feature-lanes
    if (ecnt <= CAP_H) {
        for (int i = t; i < ecnt; i += 1024) {          // rank-sort into esl
            int v = __builtin_nontemporal_load(eb + bb + i);
            int r = atomicAdd(&cw[v >> 17], 1);          // LDS return-atomic
            esl[r] = v & SRC_MASK;
        }
        __syncthreads();
        for (int nd = g; nd < 128; nd += 64) {           // register gather
            int node = n0 + nd;
            if (node >= N_NODES) continue;
            float dv = dinv[node];
            int beg = base[nd], end = base[nd + 1];
            float acc = __half2float(h1p[(size_t)node * H_MID + j]);  // self loop
            int e = beg;
            for (; e + 8 <= end; e += 8) {
                int s0 = esl[e],     s1 = esl[e + 1], s2 = esl[e + 2], s3 = esl[e + 3];
                int s4 = esl[e + 4], s5 = esl[e + 5], s6 = esl[e + 6], s7 = esl[e + 7];
                acc += __half2float(h1p[(size_t)s0 * H_MID + j])
                     + __half2float(h1p[(size_t)s1 * H_MID + j])
                     + __half2float(h1p[(size_t)s2 * H_MID + j])
                     + __half2float(h1p[(size_t)s3 * H_MID + j])
                     + __half2float(h1p[(size_t)s4 * H_MID + j])
                     + __half2float(h1p[(size_t)s5 * H_MID + j])
                     + __half2float(h1p[(size_t)s6 * H_MID + j])
                     + __half2float(h1p[(size_t)s7 * H_MID + j]);
            }
            for (; e < end; ++e) acc += __half2float(h1p[(size_t)esl[e] * H_MID + j]);
            float a = dv * acc;
            unsigned short o = __half_as_ushort(__float2half(fmaxf(a + b1[j], 0.f) * dv));
            __builtin_nontemporal_store(o, (unsigned short*)(r1p + (size_t)node * H_MID + j));
        }
    } else {
        // statistically-unreachable fallback (ecnt > +24 sigma): O(n*e) scan
        for (int nd = g; nd < 128; nd += 64) {
            int node = n0 + nd;
            if (node >= N_NODES) continue;
            float dv = dinv[node];
            float acc = __half2float(h1p[(size_t)node * H_MID + j]);
            for (int i = 0; i < ecnt; ++i) {
                int v = eb[bb + i];
                if ((v >> 17) == nd)
                    acc += __half2float(h1p[(size_t)(v & SRC_MASK) * H_MID + j]);
            }
            float a = dv * acc;
            unsigned short o = __half_as_ushort(__float2half(fmaxf(a + b1[j], 0.f) * dv));
            __builtin_nontemporal_store(o, (unsigned short*)(r1p + (size_t)node * H_MID + j));
        }
    }
}

// FUSED layer 2: per-bucket LDS rank-sort + register gather + @W2 + b2.
__global__ void __launch_bounds__(1024) k_csrg2(
    const int* __restrict__ hist, const int* __restrict__ part,
    const int* __restrict__ eb, const int* __restrict__ rp,
    const float* __restrict__ dinv, const __half* __restrict__ r1p,
    const float* __restrict__ W2, const float* __restrict__ b2,
    float* __restrict__ out) {
    __shared__ int base[129];
    __shared__ int cw[128];
    __shared__ int esl[CAP_H];
    __shared__ float a2[128 * 17];     // padded
    __shared__ float w2[H_MID * C_OUT];
    __shared__ float b2l[C_OUT];
    int b = blockIdx.x, t = threadIdx.x;
    int i0 = b * EBLK;
    int bb = hist[i0] + part[i0 >> 9];
    int bn = (b + 1 < NBUK) ? (hist[i0 + EBLK] + part[(i0 + EBLK) >> 9]) : N_EDGES;
    int ecnt = bn - bb;
    int n0 = b * 128;
    if (t < H_MID * C_OUT) w2[t] = W2[t];
    if (t >= 1024 - C_OUT) b2l[t - (1024 - C_OUT)] = b2[t - (1024 - C_OUT)];
    if (t < 128) {
        int lb = rp[n0 + t] - bb;
        base[t] = lb;
        cw[t] = lb;
    }
    if (t == 128) base[128] = ecnt;
    __syncthreads();
    int g = t >> 4, j = t & 15;
    if (ecnt <= CAP_H) {
        for (int i = t; i < ecnt; i += 1024) {
            int v = __builtin_nontemporal_load(eb + bb + i);
            int r = atomicAdd(&cw[v >> 17], 1);
            esl[r] = v & SRC_MASK;
        }
        __syncthreads();
        for (int nd = g; nd < 128; nd += 64) {
            int node = n0 + nd;
            float dv = (node < N_NODES) ? dinv[node] : 0.f;
            int beg = base[nd], end = base[nd + 1];
            float acc = (node < N_NODES) ? __half2float(r1p[(size_t)node * H_MID + j]) : 0.f;
            int e = beg;
            for (; e + 8 <= end; e += 8) {
                int s0 = esl[e],     s1 = esl[e + 1], s2 = esl[e + 2], s3 = esl[e + 3];
                int s4 = esl[e + 4], s5 = esl[e + 5], s6 = esl[e + 6], s7 = esl[e + 7];
                acc += __half2float(r1p[(size_t)s0 * H_MID + j])
                     + __half2float(r1p[(size_t)s1 * H_MID + j])
                     + __half2float(r1p[(size_t)s2 * H_MID + j])
                     + __half2float(r1p[(size_t)s3 * H_MID + j])
                     + __half2float(r1p[(size_t)s4 * H_MID + j])
                     + __half2float(r1p[(size_t)s5 * H_MID + j])
                     + __half2float(r1p[(size_t)s6 * H_MID + j])
                     + __half2float(r1p[(size_t)s7 * H_MID + j]);
            }
            for (; e < end; ++e) acc += __half2float(r1p[(size_t)esl[e] * H_MID + j]);
            a2[nd * 17 + j] = dv * acc;                  // agg2
        }
    } else {
        for (int nd = g; nd < 128; nd += 64) {
            int node = n0 + nd;
            float dv = (node < N_NODES) ? dinv[node] : 0.f;
            float acc = (node < N_NODES) ? __half2float(r1p[(size_t)node * H_MID + j]) : 0.f;
            for (int i = 0; i < ecnt; ++i) {
                int v = eb[bb + i];
                if ((v >> 17) == nd)
                    acc += __half2float(r1p[(size_t)(v & SRC_MASK) * H_MID + j]);
            }
            a2[nd * 17 + j] = dv * acc;
        }
    }
    __syncthreads();
    for (int idx = t; idx < 128 * C_OUT; idx += 1024) {
        int nd = idx / C_OUT, c = idx - nd * C_OUT;
        int node = n0 + nd;
        if (node < N_NODES) {
            float s = b2l[c];
#pragma unroll
            for (int jj = 0; jj < H_MID; ++jj) s += a2[nd * 17 + jj] * w2[jj * C_OUT + c];
            __builtin_nontemporal_store(s, &out[(size_t)node * C_OUT + c]);
        }
    }
}

extern "C" void kernel_launch(void* const* d_in, const int* in_sizes, int n_in,
                              void* d_out, int out_size, void* d_ws, size_t ws_size,
                              hipStream_t stream) {
    const float* x  = (const float*)d_in[0];
    const int*   ei = (const int*)d_in[1];     // [2, E]: row 0 = src, row 1 = dst
    const float* W1 = (const float*)d_in[2];
    const float* b1 = (const float*)d_in[3];
    const float* W2 = (const float*)d_in[4];
    const float* b2 = (const float*)d_in[5];
    float* out = (float*)d_out;

    const int* src = ei;
    const int* dst = ei + N_EDGES;

    // ws layout (4B units), ~21.3 MiB (R12 layout):
    //   rp[100352] | dinv[100352] | h1p[NSTRIDE*16 half] | r1p[same] |
    //   eb[3.2M] | hist[306176] | part[1024]
    // d_out (16MB) scratch: h1u fp32 [NSTRIDE*16] = 6.4MB -- dead after
    // k_degrp, long before k_csrg2 (sole writer of out).
    int* rp     = (int*)d_ws;
    float* dinv = (float*)(rp + NSTRIDE);
    __half* h1p = (__half*)(dinv + NSTRIDE);
    __half* r1p = h1p + (size_t)NSTRIDE * H_MID;
    int* eb     = (int*)(r1p + (size_t)NSTRIDE * H_MID);
    int* hist   = eb + N_EDGES;
    int* part   = hist + 306176;
    float* h1u  = (float*)d_out;

    k_histgemm<<<EBLK + GEMM_TILES, 256, 0, stream>>>(dst, hist, x, W1, h1u);
    k_scanA<<<NPART, 512, 0, stream>>>(hist, part);
    k_scanB<<<1, 1024, 0, stream>>>(part);
    k_part <<<EBLK, 1024, 0, stream>>>(src, dst, hist, part, eb);
    k_degrp<<<NBUK, 512, 0, stream>>>(hist, part, eb, h1u, rp, dinv, h1p);
    k_csrg1<<<NBUK, 1024, 0, stream>>>(hist, part, eb, rp, dinv, h1p, b1, r1p);
    k_csrg2<<<NBUK, 1024, 0, stream>>>(hist, part, eb, rp, dinv, r1p, W2, b2, out);
}